// Round 1
// baseline (2043.416 us; speedup 1.0000x reference)
//
#include <hip/hip_runtime.h>
#include <hip/hip_bf16.h>

#define NNODE 8192
#define DIM 512
#define NEDGE 131072
#define NLAYER 4
#define PADIDX 127

typedef float4 f4;

static __device__ __forceinline__ float bf2f(unsigned short h){
  return __uint_as_float(((unsigned int)h) << 16);
}

// Decide whether float inputs are f32 (flag=0) or bf16 (flag=1).
// Even-indexed halfwords of a bf16 array are plausible bf16 values; for an
// f32 array they are random mantissa bits -> implausible magnitudes.
__global__ void k_detect(const unsigned short* __restrict__ src, int* __restrict__ flag){
  int lane = threadIdx.x;
  float v = bf2f(src[2*lane]);
  float a = fabsf(v);
  bool good = (a > 1e-6f) && (a < 0.5f);
  unsigned long long m = __ballot(good);
  if (lane == 0) *flag = (__popcll(m) >= 32) ? 1 : 0;
}

__global__ void k_convert(const void* __restrict__ src, float* __restrict__ dst, int n,
                          const int* __restrict__ flag){
  int f = *flag;
  int i = blockIdx.x*blockDim.x + threadIdx.x;
  int stride = gridDim.x*blockDim.x;
  if (f){
    const unsigned short* s = (const unsigned short*)src;
    for (; i<n; i+=stride) dst[i] = bf2f(s[i]);
  } else {
    const float* s = (const float*)src;
    for (; i<n; i+=stride) dst[i] = s[i];
  }
}

__global__ void k_zero_i(int* __restrict__ p, int n){
  int i = blockIdx.x*blockDim.x + threadIdx.x;
  if (i<n) p[i]=0;
}

__global__ void k_count(const int* __restrict__ row, int* __restrict__ counts){
  int e = blockIdx.x*blockDim.x + threadIdx.x;
  if (e<NEDGE) atomicAdd(&counts[row[e]], 1);
}

__global__ __launch_bounds__(1024) void k_scan(const int* __restrict__ counts,
                                               int* __restrict__ offs, int* __restrict__ cursor){
  __shared__ int part[1024];
  int tid = threadIdx.x;
  int local[8]; int s = 0;
  #pragma unroll
  for (int j=0;j<8;j++){ local[j]=s; s += counts[tid*8+j]; }
  part[tid]=s;
  __syncthreads();
  for (int off=1; off<1024; off<<=1){
    int t = (tid>=off) ? part[tid-off] : 0;
    __syncthreads();
    part[tid] += t;
    __syncthreads();
  }
  int base = (tid>0) ? part[tid-1] : 0;
  #pragma unroll
  for (int j=0;j<8;j++){ int o = base + local[j]; offs[tid*8+j]=o; cursor[tid*8+j]=o; }
  if (tid==1023) offs[8192] = part[1023];
}

__global__ void k_fill(const int* __restrict__ row, int* __restrict__ cursor, int* __restrict__ elist){
  int e = blockIdx.x*blockDim.x + threadIdx.x;
  if (e<NEDGE){ int p = atomicAdd(&cursor[row[e]], 1); elist[p]=e; }
}

__global__ void k_init(const int* __restrict__ tok, const float* __restrict__ emb,
                       const float* __restrict__ coord, const float* __restrict__ vw,
                       const float* __restrict__ vb, float* __restrict__ x, float* __restrict__ v){
  int i = blockIdx.x*blockDim.x + threadIdx.x;
  if (i >= NNODE*DIM) return;
  int n = i >> 9, d = i & 511;
  int t = tok[n];
  x[i] = emb[(t<<9)|d];
  float c0 = coord[n*3+0], c1 = coord[n*3+1], c2 = coord[n*3+2];
  v[i] = c0*vw[d] + c1*vw[512+d] + c2*vw[1024+d] + vb[d];
}

// C[8192 x N] = A[8192 x 512] * B[512 x N] + bias  (+= if accumulate)
#define GBM 128
#define GBN 64
#define GBK 16
__global__ __launch_bounds__(256) void k_gemm(const float* __restrict__ A, const float* __restrict__ B,
                                              const float* __restrict__ bias, float* __restrict__ C,
                                              int N, int ldb, int accumulate){
  __shared__ float As[GBK][GBM+4];
  __shared__ float Bs[GBK][GBN+4];
  int tid = threadIdx.x;
  int bm = blockIdx.y * GBM;
  int bn = blockIdx.x * GBN;
  int tx = tid & 15;
  int ty = tid >> 4;
  float acc[8][4];
  #pragma unroll
  for (int i=0;i<8;i++)
    #pragma unroll
    for (int j=0;j<4;j++) acc[i][j]=0.f;

  for (int k0=0; k0<512; k0+=GBK){
    #pragma unroll
    for (int s=0;s<2;s++){
      int idx = tid + 256*s;
      int r = idx >> 2;
      int c = (idx & 3) * 4;
      f4 a = *(const f4*)(A + (size_t)(bm+r)*512 + k0 + c);
      As[c+0][r]=a.x; As[c+1][r]=a.y; As[c+2][r]=a.z; As[c+3][r]=a.w;
    }
    {
      int r = tid >> 4;
      int c = (tid & 15) * 4;
      f4 b = *(const f4*)(B + (size_t)(k0+r)*ldb + bn + c);
      *(f4*)&Bs[r][c] = b;
    }
    __syncthreads();
    #pragma unroll
    for (int kk=0;kk<GBK;kk++){
      f4 bv = *(const f4*)&Bs[kk][tx*4];
      f4 a0 = *(const f4*)&As[kk][ty*8];
      f4 a1 = *(const f4*)&As[kk][ty*8+4];
      float av[8] = {a0.x,a0.y,a0.z,a0.w,a1.x,a1.y,a1.z,a1.w};
      float bw[4] = {bv.x,bv.y,bv.z,bv.w};
      #pragma unroll
      for (int i=0;i<8;i++)
        #pragma unroll
        for (int j=0;j<4;j++) acc[i][j] += av[i]*bw[j];
    }
    __syncthreads();
  }
  #pragma unroll
  for (int i=0;i<8;i++){
    int row = bm + ty*8 + i;
    #pragma unroll
    for (int j=0;j<4;j++){
      int col = bn + tx*4 + j;
      float val = acc[i][j] + bias[col];
      size_t o = (size_t)row*N + col;
      if (accumulate) C[o] += val; else C[o] = val;
    }
  }
}

// ew[e] = dot(q[row[e]], kv[col[e], 0:512]) — one wave per edge
__global__ __launch_bounds__(256) void k_edges(const int* __restrict__ ei, const float* __restrict__ q,
                                               const float* __restrict__ kv, float* __restrict__ ew){
  int e = blockIdx.x*4 + (threadIdx.x>>6);
  int lane = threadIdx.x & 63;
  if (e >= NEDGE) return;
  int r = ei[e], c = ei[NEDGE+e];
  const f4* qp = (const f4*)(q + (size_t)r*DIM);
  const f4* kp = (const f4*)(kv + (size_t)c*(3*DIM));
  f4 a0 = qp[lane], a1 = qp[lane+64];
  f4 b0 = kp[lane], b1 = kp[lane+64];
  float s = a0.x*b0.x + a0.y*b0.y + a0.z*b0.z + a0.w*b0.w
          + a1.x*b1.x + a1.y*b1.y + a1.z*b1.z + a1.w*b1.w;
  #pragma unroll
  for (int o=32;o;o>>=1) s += __shfl_xor(s, o, 64);
  if (lane==0) ew[e]=s;
}

// vv[n,d] = kv[n, 1024+d] * v[n,d]   (precompute gated vector source)
__global__ void k_vv(const float* __restrict__ kv, const float* __restrict__ v, float* __restrict__ vv){
  int i = blockIdx.x*blockDim.x + threadIdx.x;
  if (i>=NNODE*DIM) return;
  int n = i>>9, d = i&511;
  vv[i] = kv[(size_t)n*1536 + 1024 + d] * v[i];
}

// Per destination node: accumulate scalar + vector messages over its CSR edge list.
__global__ __launch_bounds__(256) void k_agg(const int* __restrict__ offs, const int* __restrict__ elist,
                                             const int* __restrict__ eicol, const float* __restrict__ ew,
                                             const float* __restrict__ kv, const float* __restrict__ vvp,
                                             float* __restrict__ x, float* __restrict__ aggv){
  int n = blockIdx.x, t = threadIdx.x;
  int beg = offs[n], end = offs[n+1];
  float s0=0.f, s1=0.f, a0=0.f, a1=0.f;
  for (int j=beg;j<end;j++){
    int e = elist[j];
    float w = ew[e];
    int c = eicol[e];
    const float* vs = kv + (size_t)c*1536 + 512;
    const float* pv = vvp + (size_t)c*512;
    s0 += w*vs[t];     s1 += w*vs[t+256];
    a0 += w*pv[t];     a1 += w*pv[t+256];
  }
  size_t base = (size_t)n*512;
  x[base+t]    += s0; x[base+t+256] += s1;
  aggv[base+t]  = a0; aggv[base+t+256] = a1;
}

__global__ void k_out(const int* __restrict__ tok, const float* __restrict__ x,
                      float* __restrict__ out, int out_size){
  int i = blockIdx.x*blockDim.x + threadIdx.x;
  if (i>=out_size) return;
  if (i < NNODE*DIM){
    int n = i>>9;
    out[i] = (tok[n]==PADIDX) ? 0.f : x[i];
  } else {
    int m = i - NNODE*DIM;
    out[i] = (m < NNODE && tok[m]==PADIDX) ? 1.f : 0.f;
  }
}

extern "C" void kernel_launch(void* const* d_in, const int* in_sizes, int n_in,
                              void* d_out, int out_size, void* d_ws, size_t ws_size,
                              hipStream_t stream){
  (void)in_sizes; (void)n_in; (void)ws_size;
  const int*  tok   = (const int*)d_in[0];
  const void* coord = d_in[1];
  // d_in[2] src_distance, d_in[3] src_edge_type: unused by reference
  const int*  ei    = (const int*)d_in[4];
  const void* emb   = d_in[5];
  const void* vpw   = d_in[6];
  const void* vpb   = d_in[7];
  const void* Wq    = d_in[8];
  const void* bq    = d_in[9];
  const void* Wkv   = d_in[10];
  const void* bkv   = d_in[11];
  const void* Wvm   = d_in[12];
  const void* bvm   = d_in[13];

  char* p = (char*)d_ws;
  auto alloc = [&](size_t nbytes)->char*{ char* r = p; p += (nbytes + 255) & ~(size_t)255; return r; };
  float* x     = (float*)alloc((size_t)NNODE*DIM*4);
  float* v     = (float*)alloc((size_t)NNODE*DIM*4);
  float* q     = (float*)alloc((size_t)NNODE*DIM*4);
  float* kv    = (float*)alloc((size_t)NNODE*3*DIM*4);
  float* vv    = (float*)alloc((size_t)NNODE*DIM*4);
  float* aggv  = (float*)alloc((size_t)NNODE*DIM*4);
  float* ew    = (float*)alloc((size_t)NEDGE*4);
  float* cEmb  = (float*)alloc((size_t)128*DIM*4);
  float* cCoord= (float*)alloc((size_t)NNODE*3*4);
  float* cVw   = (float*)alloc((size_t)3*DIM*4);
  float* cVb   = (float*)alloc((size_t)DIM*4);
  float* cWq   = (float*)alloc((size_t)NLAYER*DIM*DIM*4);
  float* cbq   = (float*)alloc((size_t)NLAYER*DIM*4);
  float* cWkv  = (float*)alloc((size_t)NLAYER*DIM*3*DIM*4);
  float* cbkv  = (float*)alloc((size_t)NLAYER*3*DIM*4);
  float* cWvm  = (float*)alloc((size_t)NLAYER*DIM*DIM*4);
  float* cbvm  = (float*)alloc((size_t)NLAYER*DIM*4);
  int* counts  = (int*)alloc(8192*4);
  int* offs    = (int*)alloc(8193*4);
  int* cursor  = (int*)alloc(8192*4);
  int* elist   = (int*)alloc((size_t)NEDGE*4);
  int* flag    = (int*)alloc(4);

  k_detect<<<1,64,0,stream>>>((const unsigned short*)Wq, flag);
  auto conv = [&](const void* s, float* d, int n){
    int blocks = (n+255)/256; if (blocks>8192) blocks=8192;
    k_convert<<<blocks,256,0,stream>>>(s, d, n, flag);
  };
  conv(coord, cCoord, NNODE*3);
  conv(emb,   cEmb,   128*DIM);     // only token rows 0..127 are reachable
  conv(vpw,   cVw,    3*DIM);
  conv(vpb,   cVb,    DIM);
  conv(Wq,    cWq,    NLAYER*DIM*DIM);
  conv(bq,    cbq,    NLAYER*DIM);
  conv(Wkv,   cWkv,   NLAYER*DIM*3*DIM);
  conv(bkv,   cbkv,   NLAYER*3*DIM);
  conv(Wvm,   cWvm,   NLAYER*DIM*DIM);
  conv(bvm,   cbvm,   NLAYER*DIM);

  // CSR of edges by destination (row) — edge_index is a fixed input, rebuilt each call
  k_zero_i<<<32,256,0,stream>>>(counts, 8192);
  k_count<<<NEDGE/256,256,0,stream>>>(ei, counts);
  k_scan<<<1,1024,0,stream>>>(counts, offs, cursor);
  k_fill<<<NEDGE/256,256,0,stream>>>(ei, cursor, elist);

  k_init<<<(NNODE*DIM)/256,256,0,stream>>>(tok, cEmb, cCoord, cVw, cVb, x, v);

  for (int l=0;l<NLAYER;l++){
    const float* Wq_l  = cWq  + (size_t)l*DIM*DIM;
    const float* bq_l  = cbq  + (size_t)l*DIM;
    const float* Wkv_l = cWkv + (size_t)l*DIM*3*DIM;
    const float* bkv_l = cbkv + (size_t)l*3*DIM;
    const float* Wvm_l = cWvm + (size_t)l*DIM*DIM;
    const float* bvm_l = cbvm + (size_t)l*DIM;
    k_gemm<<<dim3(DIM/GBN,   NNODE/GBM),256,0,stream>>>(x,    Wq_l,  bq_l,  q,  DIM,   DIM,   0);
    k_gemm<<<dim3(3*DIM/GBN, NNODE/GBM),256,0,stream>>>(x,    Wkv_l, bkv_l, kv, 3*DIM, 3*DIM, 0);
    k_edges<<<NEDGE/4,256,0,stream>>>(ei, q, kv, ew);
    k_vv<<<(NNODE*DIM)/256,256,0,stream>>>(kv, v, vv);
    k_agg<<<NNODE,256,0,stream>>>(offs, elist, ei+NEDGE, ew, kv, vv, x, aggv);
    k_gemm<<<dim3(DIM/GBN,   NNODE/GBM),256,0,stream>>>(aggv, Wvm_l, bvm_l, v,  DIM,   DIM,   1);
  }

  int ob = (out_size+255)/256;
  k_out<<<ob,256,0,stream>>>(tok, x, (float*)d_out, out_size);
}

// Round 2
// 1176.832 us; speedup vs baseline: 1.7364x; 1.7364x over previous
//
#include <hip/hip_runtime.h>
#include <hip/hip_bf16.h>

#define NNODE 8192
#define DIM 512
#define NEDGE 131072
#define NLAYER 4
#define PADIDX 127

typedef float4 f4;
typedef __attribute__((ext_vector_type(8))) short s16x8;
typedef __attribute__((ext_vector_type(4))) float f32x4;

static __device__ __forceinline__ float bf2f(unsigned short h){
  return __uint_as_float(((unsigned int)h) << 16);
}
static __device__ __forceinline__ unsigned short f2bf(float f){
  unsigned int u = __float_as_uint(f);
  u += 0x7FFFu + ((u >> 16) & 1u);
  return (unsigned short)(u >> 16);
}

// ---- dtype detect: even halfwords of a bf16 array are plausible bf16 values ----
__global__ void k_detect(const unsigned short* __restrict__ src, int* __restrict__ flag){
  int lane = threadIdx.x;
  float v = bf2f(src[2*lane]);
  float a = fabsf(v);
  bool good = (a > 1e-6f) && (a < 0.5f);
  unsigned long long m = __ballot(good);
  if (lane == 0) *flag = (__popcll(m) >= 32) ? 1 : 0;
}

__global__ void k_convert(const void* __restrict__ src, float* __restrict__ dst, int n,
                          const int* __restrict__ flag){
  int f = *flag;
  int i = blockIdx.x*blockDim.x + threadIdx.x;
  int stride = gridDim.x*blockDim.x;
  if (f){
    const unsigned short* s = (const unsigned short*)src;
    for (; i<n; i+=stride) dst[i] = bf2f(s[i]);
  } else {
    const float* s = (const float*)src;
    for (; i<n; i+=stride) dst[i] = s[i];
  }
}

// Transpose-convert weights: src matrices [512][C] (f32 or bf16) -> dst [C][512] bf16.
// blockIdx.z selects the layer matrix.
__global__ void k_convT(const void* __restrict__ src, unsigned short* __restrict__ dst,
                        int C, const int* __restrict__ flag){
  int f = *flag;
  size_t mat = (size_t)blockIdx.z * 512 * C;
  int i = blockIdx.x*blockDim.x + threadIdx.x;
  if (i >= 512*C) return;
  int r = i & 511;      // input row (k)
  int c = i >> 9;       // input col (n) == dst row
  size_t si = mat + (size_t)r*C + c;
  unsigned short o;
  if (f) o = ((const unsigned short*)src)[si];
  else   o = f2bf(((const float*)src)[si]);
  dst[mat + i] = o;     // i == c*512 + r
}

// ---- CSR build ----
__global__ void k_zero_i(int* __restrict__ p, int n){
  int i = blockIdx.x*blockDim.x + threadIdx.x;
  if (i<n) p[i]=0;
}

__global__ void k_count(const int* __restrict__ row, int* __restrict__ counts){
  int e = blockIdx.x*blockDim.x + threadIdx.x;
  if (e<NEDGE) atomicAdd(&counts[row[e]], 1);
}

__global__ __launch_bounds__(1024) void k_scan(const int* __restrict__ counts,
                                               int* __restrict__ offs, int* __restrict__ cursor){
  __shared__ int part[1024];
  int tid = threadIdx.x;
  int local[8]; int s = 0;
  #pragma unroll
  for (int j=0;j<8;j++){ local[j]=s; s += counts[tid*8+j]; }
  part[tid]=s;
  __syncthreads();
  for (int off=1; off<1024; off<<=1){
    int t = (tid>=off) ? part[tid-off] : 0;
    __syncthreads();
    part[tid] += t;
    __syncthreads();
  }
  int base = (tid>0) ? part[tid-1] : 0;
  #pragma unroll
  for (int j=0;j<8;j++){ int o = base + local[j]; offs[tid*8+j]=o; cursor[tid*8+j]=o; }
  if (tid==1023) offs[8192] = part[1023];
}

__global__ void k_fill(const int* __restrict__ row, int* __restrict__ cursor, int* __restrict__ elist){
  int e = blockIdx.x*blockDim.x + threadIdx.x;
  if (e<NEDGE){ int p = atomicAdd(&cursor[row[e]], 1); elist[p]=e; }
}

// ---- init: x = embed[tok], v = coord @ vec_proj + b ; also bf16 mirror of x ----
__global__ void k_init(const int* __restrict__ tok, const float* __restrict__ emb,
                       const float* __restrict__ coord, const float* __restrict__ vw,
                       const float* __restrict__ vb, float* __restrict__ x,
                       float* __restrict__ v, unsigned short* __restrict__ xbf){
  int i = blockIdx.x*blockDim.x + threadIdx.x;
  if (i >= NNODE*DIM) return;
  int n = i >> 9, d = i & 511;
  int t = tok[n];
  float xv = emb[(t<<9)|d];
  x[i] = xv;
  xbf[i] = f2bf(xv);
  float c0 = coord[n*3+0], c1 = coord[n*3+1], c2 = coord[n*3+2];
  v[i] = c0*vw[d] + c1*vw[512+d] + c2*vw[1024+d] + vb[d];
}

// ---- bf16 MFMA GEMM: C[8192 x ldc] (f32) = A[8192 x 512](bf16) * Bt[ldc x 512]^T (bf16) + bias ----
// m97 structure: 128x128 tile, BK=64, 4 waves (2x2), 4x4 frags of 16x16x32.
// LDS linear (global_load_lds), XOR slot-swizzle applied on the GLOBAL source and the ds_read.
#define BM 128
#define BN 128
#define BK 64

static __device__ __forceinline__ void gload16(const void* g, void* l){
  __builtin_amdgcn_global_load_lds(
      (const __attribute__((address_space(1))) void*)g,
      (__attribute__((address_space(3))) void*)l, 16, 0, 0);
}

__global__ __launch_bounds__(256) void k_mgemm(const unsigned short* __restrict__ A,
                                               const unsigned short* __restrict__ Bt,
                                               const float* __restrict__ bias,
                                               float* __restrict__ C,
                                               int ldc, int accumulate){
  __shared__ alignas(16) unsigned short As[BM*BK];
  __shared__ alignas(16) unsigned short Bs[BN*BK];
  int tid  = threadIdx.x;
  int lane = tid & 63;
  int w    = tid >> 6;
  int wr   = (w >> 1) * 64;
  int wc   = (w & 1) * 64;
  int bm   = blockIdx.y * BM;
  int bn   = blockIdx.x * BN;

  f32x4 acc[4][4];
  #pragma unroll
  for (int m=0;m<4;m++)
    #pragma unroll
    for (int n=0;n<4;n++) acc[m][n] = (f32x4){0.f,0.f,0.f,0.f};

  int srow = tid >> 3;   // 0..31 row within a 32-row staging issue
  int sp   = tid & 7;    // 16B slot position within the 128B row
  char* AsB = (char*)As;
  char* BsB = (char*)Bs;

  for (int kt = 0; kt < 512; kt += BK){
    if (kt) __syncthreads();
    // stage A tile [128][64] bf16 (4 issues x 4096B); source pre-swizzled so
    // LDS physical slot sp holds logical k-slot (sp ^ (row&7))
    #pragma unroll
    for (int i=0;i<4;i++){
      int row  = i*32 + srow;
      int slot = sp ^ (row & 7);
      gload16((const char*)A + (((size_t)(bm + row)) << 10) + (size_t)((kt + slot*8) << 1),
              AsB + i*4096 + w*1024);
    }
    #pragma unroll
    for (int i=0;i<4;i++){
      int row  = i*32 + srow;
      int slot = sp ^ (row & 7);
      gload16((const char*)Bt + (((size_t)(bn + row)) << 10) + (size_t)((kt + slot*8) << 1),
              BsB + i*4096 + w*1024);
    }
    __syncthreads();

    s16x8 af[4][2], bfr[4][2];
    #pragma unroll
    for (int m=0;m<4;m++){
      int row = wr + m*16 + (lane & 15);
      #pragma unroll
      for (int kk=0;kk<2;kk++){
        int slot = kk*4 + (lane >> 4);
        af[m][kk] = *(const s16x8*)(AsB + row*128 + ((slot ^ (row & 7)) << 4));
      }
    }
    #pragma unroll
    for (int n=0;n<4;n++){
      int row = wc + n*16 + (lane & 15);
      #pragma unroll
      for (int kk=0;kk<2;kk++){
        int slot = kk*4 + (lane >> 4);
        bfr[n][kk] = *(const s16x8*)(BsB + row*128 + ((slot ^ (row & 7)) << 4));
      }
    }
    #pragma unroll
    for (int kk=0;kk<2;kk++)
      #pragma unroll
      for (int m=0;m<4;m++)
        #pragma unroll
        for (int n=0;n<4;n++)
          acc[m][n] = __builtin_amdgcn_mfma_f32_16x16x32_bf16(af[m][kk], bfr[n][kk], acc[m][n], 0, 0, 0);
  }

  // C/D layout (HW-verified): col = lane&15, row = (lane>>4)*4 + j
  int colb = bn + wc + (lane & 15);
  int rowb = bm + wr + ((lane >> 4) << 2);
  float bb[4];
  #pragma unroll
  for (int n=0;n<4;n++) bb[n] = bias[colb + n*16];
  #pragma unroll
  for (int m=0;m<4;m++){
    #pragma unroll
    for (int n=0;n<4;n++){
      #pragma unroll
      for (int j=0;j<4;j++){
        size_t o = (size_t)(rowb + m*16 + j)*ldc + (colb + n*16);
        float val = acc[m][n][j] + bb[n];
        if (accumulate) C[o] += val; else C[o] = val;
      }
    }
  }
}

// ---- edge scores: ew[e] = dot(q[row[e]], kv[col[e], 0:512]) — one wave per edge ----
__global__ __launch_bounds__(256) void k_edges(const int* __restrict__ ei, const float* __restrict__ q,
                                               const float* __restrict__ kv, float* __restrict__ ew){
  int e = blockIdx.x*4 + (threadIdx.x>>6);
  int lane = threadIdx.x & 63;
  if (e >= NEDGE) return;
  int r = ei[e], c = ei[NEDGE+e];
  const f4* qp = (const f4*)(q + (size_t)r*DIM);
  const f4* kp = (const f4*)(kv + (size_t)c*(3*DIM));
  f4 a0 = qp[lane], a1 = qp[lane+64];
  f4 b0 = kp[lane], b1 = kp[lane+64];
  float s = a0.x*b0.x + a0.y*b0.y + a0.z*b0.z + a0.w*b0.w
          + a1.x*b1.x + a1.y*b1.y + a1.z*b1.z + a1.w*b1.w;
  #pragma unroll
  for (int o=32;o;o>>=1) s += __shfl_xor(s, o, 64);
  if (lane==0) ew[e]=s;
}

// ---- aggregate per destination node (fuses the v-gating) ----
__global__ __launch_bounds__(256) void k_agg(const int* __restrict__ offs, const int* __restrict__ elist,
                                             const int* __restrict__ eicol, const float* __restrict__ ew,
                                             const float* __restrict__ kv, const float* __restrict__ v,
                                             float* __restrict__ x, unsigned short* __restrict__ xbf,
                                             unsigned short* __restrict__ aggv_bf){
  int n = blockIdx.x, t = threadIdx.x;
  int beg = offs[n], end = offs[n+1];
  float s0=0.f, s1=0.f, a0=0.f, a1=0.f;
  for (int j=beg;j<end;j++){
    int e = elist[j];
    float wgt = ew[e];
    int c = eicol[e];
    const float* kvc = kv + (size_t)c*1536;
    const float* vc  = v  + (size_t)c*512;
    s0 += wgt*kvc[512+t];
    s1 += wgt*kvc[768+t];
    a0 += wgt*kvc[1024+t]*vc[t];
    a1 += wgt*kvc[1280+t]*vc[t+256];
  }
  size_t base = (size_t)n*512;
  float x0 = x[base+t] + s0;
  float x1 = x[base+t+256] + s1;
  x[base+t] = x0;       x[base+t+256] = x1;
  xbf[base+t] = f2bf(x0); xbf[base+t+256] = f2bf(x1);
  aggv_bf[base+t] = f2bf(a0); aggv_bf[base+t+256] = f2bf(a1);
}

__global__ void k_out(const int* __restrict__ tok, const float* __restrict__ x,
                      float* __restrict__ out, int out_size){
  int i = blockIdx.x*blockDim.x + threadIdx.x;
  if (i>=out_size) return;
  if (i < NNODE*DIM){
    int n = i>>9;
    out[i] = (tok[n]==PADIDX) ? 0.f : x[i];
  } else {
    int m = i - NNODE*DIM;
    out[i] = (m < NNODE && tok[m]==PADIDX) ? 1.f : 0.f;
  }
}

extern "C" void kernel_launch(void* const* d_in, const int* in_sizes, int n_in,
                              void* d_out, int out_size, void* d_ws, size_t ws_size,
                              hipStream_t stream){
  (void)in_sizes; (void)n_in; (void)ws_size;
  const int*  tok   = (const int*)d_in[0];
  const void* coord = d_in[1];
  // d_in[2] src_distance, d_in[3] src_edge_type: unused by reference
  const int*  ei    = (const int*)d_in[4];
  const void* emb   = d_in[5];
  const void* vpw   = d_in[6];
  const void* vpb   = d_in[7];
  const void* Wq    = d_in[8];
  const void* bq    = d_in[9];
  const void* Wkv   = d_in[10];
  const void* bkv   = d_in[11];
  const void* Wvm   = d_in[12];
  const void* bvm   = d_in[13];

  char* p = (char*)d_ws;
  auto alloc = [&](size_t nbytes)->char*{ char* r = p; p += (nbytes + 255) & ~(size_t)255; return r; };
  float* x      = (float*)alloc((size_t)NNODE*DIM*4);
  float* v      = (float*)alloc((size_t)NNODE*DIM*4);
  float* q      = (float*)alloc((size_t)NNODE*DIM*4);
  float* kv     = (float*)alloc((size_t)NNODE*3*DIM*4);
  float* ew     = (float*)alloc((size_t)NEDGE*4);
  unsigned short* xbf    = (unsigned short*)alloc((size_t)NNODE*DIM*2);
  unsigned short* aggvbf = (unsigned short*)alloc((size_t)NNODE*DIM*2);
  unsigned short* WqT    = (unsigned short*)alloc((size_t)NLAYER*DIM*DIM*2);
  unsigned short* WkvT   = (unsigned short*)alloc((size_t)NLAYER*DIM*3*DIM*2);
  unsigned short* WvmT   = (unsigned short*)alloc((size_t)NLAYER*DIM*DIM*2);
  float* cEmb   = (float*)alloc((size_t)128*DIM*4);
  float* cCoord = (float*)alloc((size_t)NNODE*3*4);
  float* cVw    = (float*)alloc((size_t)3*DIM*4);
  float* cVb    = (float*)alloc((size_t)DIM*4);
  float* cbq    = (float*)alloc((size_t)NLAYER*DIM*4);
  float* cbkv   = (float*)alloc((size_t)NLAYER*3*DIM*4);
  float* cbvm   = (float*)alloc((size_t)NLAYER*DIM*4);
  int* counts   = (int*)alloc(8192*4);
  int* offs     = (int*)alloc(8193*4);
  int* cursor   = (int*)alloc(8192*4);
  int* elist    = (int*)alloc((size_t)NEDGE*4);
  int* flag     = (int*)alloc(4);

  k_detect<<<1,64,0,stream>>>((const unsigned short*)Wq, flag);
  auto conv = [&](const void* s, float* d, int n){
    int blocks = (n+255)/256; if (blocks>8192) blocks=8192;
    k_convert<<<blocks,256,0,stream>>>(s, d, n, flag);
  };
  conv(coord, cCoord, NNODE*3);
  conv(emb,   cEmb,   128*DIM);   // only token rows 0..127 are reachable
  conv(vpw,   cVw,    3*DIM);
  conv(vpb,   cVb,    DIM);
  conv(bq,    cbq,    NLAYER*DIM);
  conv(bkv,   cbkv,   NLAYER*3*DIM);
  conv(bvm,   cbvm,   NLAYER*DIM);
  // transpose-convert weights to bf16 B^T layout [N][K]
  k_convT<<<dim3((512*512+255)/256,1,NLAYER),256,0,stream>>>(Wq,  WqT,  512,  flag);
  k_convT<<<dim3((512*1536+255)/256,1,NLAYER),256,0,stream>>>(Wkv, WkvT, 1536, flag);
  k_convT<<<dim3((512*512+255)/256,1,NLAYER),256,0,stream>>>(Wvm, WvmT, 512,  flag);

  // CSR of edges by destination
  k_zero_i<<<32,256,0,stream>>>(counts, 8192);
  k_count<<<NEDGE/256,256,0,stream>>>(ei, counts);
  k_scan<<<1,1024,0,stream>>>(counts, offs, cursor);
  k_fill<<<NEDGE/256,256,0,stream>>>(ei, cursor, elist);

  k_init<<<(NNODE*DIM)/256,256,0,stream>>>(tok, cEmb, cCoord, cVw, cVb, x, v, xbf);

  for (int l=0;l<NLAYER;l++){
    const unsigned short* WqT_l  = WqT  + (size_t)l*DIM*DIM;
    const unsigned short* WkvT_l = WkvT + (size_t)l*DIM*3*DIM;
    const unsigned short* WvmT_l = WvmT + (size_t)l*DIM*DIM;
    const float* bq_l  = cbq  + (size_t)l*DIM;
    const float* bkv_l = cbkv + (size_t)l*3*DIM;
    const float* bvm_l = cbvm + (size_t)l*DIM;
    k_mgemm<<<dim3(DIM/BN,   NNODE/BM),256,0,stream>>>(xbf,    WqT_l,  bq_l,  q,  DIM,   0);
    k_mgemm<<<dim3(3*DIM/BN, NNODE/BM),256,0,stream>>>(xbf,    WkvT_l, bkv_l, kv, 3*DIM, 0);
    k_edges<<<NEDGE/4,256,0,stream>>>(ei, q, kv, ew);
    k_agg<<<NNODE,256,0,stream>>>(offs, elist, ei+NEDGE, ew, kv, v, x, xbf, aggvbf);
    k_mgemm<<<dim3(DIM/BN,   NNODE/BM),256,0,stream>>>(aggvbf, WvmT_l, bvm_l, v,  DIM,   1);
  }

  int ob = (out_size+255)/256;
  k_out<<<ob,256,0,stream>>>(tok, x, (float*)d_out, out_size);
}

// Round 4
// 688.502 us; speedup vs baseline: 2.9679x; 1.7093x over previous
//
#include <hip/hip_runtime.h>
#include <hip/hip_bf16.h>

#define NNODE 8192
#define DIM 512
#define NEDGE 131072
#define NLAYER 4
#define PADIDX 127

typedef float4 f4;
typedef __attribute__((ext_vector_type(8))) short s16x8;
typedef __attribute__((ext_vector_type(4))) float f32x4;

static __device__ __forceinline__ float bf2f(unsigned short h){
  return __uint_as_float(((unsigned int)h) << 16);
}
static __device__ __forceinline__ unsigned short f2bf(float f){
  unsigned int u = __float_as_uint(f);
  u += 0x7FFFu + ((u >> 16) & 1u);
  return (unsigned short)(u >> 16);
}
static __device__ __forceinline__ float blo(unsigned int u){ return __uint_as_float(u << 16); }
static __device__ __forceinline__ float bhi(unsigned int u){ return __uint_as_float(u & 0xFFFF0000u); }
static __device__ __forceinline__ unsigned int pack2(float a, float b){
  return (unsigned int)f2bf(a) | ((unsigned int)f2bf(b) << 16);
}

// ---- dtype detect: even halfwords of a bf16 array are plausible bf16 values ----
__global__ void k_detect(const unsigned short* __restrict__ src, int* __restrict__ flag){
  int lane = threadIdx.x;
  float v = bf2f(src[2*lane]);
  float a = fabsf(v);
  bool good = (a > 1e-6f) && (a < 0.5f);
  unsigned long long m = __ballot(good);
  if (lane == 0) *flag = (__popcll(m) >= 32) ? 1 : 0;
}

__global__ void k_convert(const void* __restrict__ src, float* __restrict__ dst, int n,
                          const int* __restrict__ flag){
  int f = *flag;
  int i = blockIdx.x*blockDim.x + threadIdx.x;
  int stride = gridDim.x*blockDim.x;
  if (f){
    const unsigned short* s = (const unsigned short*)src;
    for (; i<n; i+=stride) dst[i] = bf2f(s[i]);
  } else {
    const float* s = (const float*)src;
    for (; i<n; i+=stride) dst[i] = s[i];
  }
}

// Transpose-convert weights: src [L][512][C] -> dst rows (dstOff+c), layer stride dstStride.
__global__ void k_convT(const void* __restrict__ src, unsigned short* __restrict__ dst,
                        int C, int dstOff, int dstStride, const int* __restrict__ flag){
  int f = *flag;
  int i = blockIdx.x*blockDim.x + threadIdx.x;
  if (i >= 512*C) return;
  int r = i & 511;      // input row (k)
  int c = i >> 9;       // input col (n) -> dst row dstOff+c
  size_t si = (size_t)blockIdx.z*512*C + (size_t)r*C + c;
  unsigned short o;
  if (f) o = ((const unsigned short*)src)[si];
  else   o = f2bf(((const float*)src)[si]);
  dst[(size_t)blockIdx.z*dstStride + (size_t)(dstOff + c)*512 + r] = o;
}

// combined qkv bias [L][2048] f32
__global__ void k_bias(const void* __restrict__ bq, const void* __restrict__ bkv,
                       float* __restrict__ dst, const int* __restrict__ flag){
  int f = *flag;
  int gid = blockIdx.x*blockDim.x + threadIdx.x;
  if (gid >= NLAYER*2048) return;
  int l = gid >> 11, j = gid & 2047;
  float val;
  if (j < 512)
    val = f ? bf2f(((const unsigned short*)bq)[l*512+j]) : ((const float*)bq)[l*512+j];
  else
    val = f ? bf2f(((const unsigned short*)bkv)[l*1536 + j-512]) : ((const float*)bkv)[l*1536 + j-512];
  dst[gid] = val;
}

// ---- CSR build (stores source col directly) ----
__global__ void k_zero_i(int* __restrict__ p, int n){
  int i = blockIdx.x*blockDim.x + threadIdx.x;
  if (i<n) p[i]=0;
}

__global__ void k_count(const int* __restrict__ row, int* __restrict__ counts){
  int e = blockIdx.x*blockDim.x + threadIdx.x;
  if (e<NEDGE) atomicAdd(&counts[row[e]], 1);
}

__global__ __launch_bounds__(1024) void k_scan(const int* __restrict__ counts,
                                               int* __restrict__ offs, int* __restrict__ cursor){
  __shared__ int part[1024];
  int tid = threadIdx.x;
  int local[8]; int s = 0;
  #pragma unroll
  for (int j=0;j<8;j++){ local[j]=s; s += counts[tid*8+j]; }
  part[tid]=s;
  __syncthreads();
  for (int off=1; off<1024; off<<=1){
    int t = (tid>=off) ? part[tid-off] : 0;
    __syncthreads();
    part[tid] += t;
    __syncthreads();
  }
  int base = (tid>0) ? part[tid-1] : 0;
  #pragma unroll
  for (int j=0;j<8;j++){ int o = base + local[j]; offs[tid*8+j]=o; cursor[tid*8+j]=o; }
  if (tid==1023) offs[8192] = part[1023];
}

__global__ void k_fill(const int* __restrict__ ei, int* __restrict__ cursor, int* __restrict__ ecol){
  int e = blockIdx.x*blockDim.x + threadIdx.x;
  if (e<NEDGE){ int p = atomicAdd(&cursor[ei[e]], 1); ecol[p] = ei[NEDGE+e]; }
}

// ---- init: x = embed[tok], v = coord @ vec_proj + b ; bf16 mirror of x ----
__global__ void k_init(const int* __restrict__ tok, const float* __restrict__ emb,
                       const float* __restrict__ coord, const float* __restrict__ vw,
                       const float* __restrict__ vb, float* __restrict__ x,
                       float* __restrict__ v, unsigned short* __restrict__ xbf){
  int i = blockIdx.x*blockDim.x + threadIdx.x;
  if (i >= NNODE*DIM) return;
  int n = i >> 9, d = i & 511;
  int t = tok[n];
  float xv = emb[(t<<9)|d];
  x[i] = xv;
  xbf[i] = f2bf(xv);
  float c0 = coord[n*3+0], c1 = coord[n*3+1], c2 = coord[n*3+2];
  v[i] = c0*vw[d] + c1*vw[512+d] + c2*vw[1024+d] + vb[d];
}

// ---- bf16 MFMA GEMM (m97 structure, 128x128 tile, BK=64, 4 waves, 16x16x32) ----
// mode 0: f32 store; 1: f32 +=; 2: bf16 store
#define BM 128
#define BN 128
#define BK 64

static __device__ __forceinline__ void gload16(const void* g, void* l){
  __builtin_amdgcn_global_load_lds(
      (const __attribute__((address_space(1))) void*)g,
      (__attribute__((address_space(3))) void*)l, 16, 0, 0);
}

__global__ __launch_bounds__(256) void k_mgemm(const unsigned short* __restrict__ A,
                                               const unsigned short* __restrict__ Bt,
                                               const float* __restrict__ bias,
                                               void* __restrict__ C,
                                               int ldc, int mode){
  __shared__ alignas(16) unsigned short As[BM*BK];
  __shared__ alignas(16) unsigned short Bs[BN*BK];
  int tid  = threadIdx.x;
  int lane = tid & 63;
  int w    = tid >> 6;
  int wr   = (w >> 1) * 64;
  int wc   = (w & 1) * 64;
  int bm   = blockIdx.y * BM;
  int bn   = blockIdx.x * BN;

  f32x4 acc[4][4];
  #pragma unroll
  for (int m=0;m<4;m++)
    #pragma unroll
    for (int n=0;n<4;n++) acc[m][n] = (f32x4){0.f,0.f,0.f,0.f};

  int srow = tid >> 3;
  int sp   = tid & 7;
  char* AsB = (char*)As;
  char* BsB = (char*)Bs;

  for (int kt = 0; kt < 512; kt += BK){
    if (kt) __syncthreads();
    #pragma unroll
    for (int i=0;i<4;i++){
      int row  = i*32 + srow;
      int slot = sp ^ (row & 7);
      gload16((const char*)A + (((size_t)(bm + row)) << 10) + (size_t)((kt + slot*8) << 1),
              AsB + i*4096 + w*1024);
    }
    #pragma unroll
    for (int i=0;i<4;i++){
      int row  = i*32 + srow;
      int slot = sp ^ (row & 7);
      gload16((const char*)Bt + (((size_t)(bn + row)) << 10) + (size_t)((kt + slot*8) << 1),
              BsB + i*4096 + w*1024);
    }
    __syncthreads();

    s16x8 af[4][2], bfr[4][2];
    #pragma unroll
    for (int m=0;m<4;m++){
      int row = wr + m*16 + (lane & 15);
      #pragma unroll
      for (int kk=0;kk<2;kk++){
        int slot = kk*4 + (lane >> 4);
        af[m][kk] = *(const s16x8*)(AsB + row*128 + ((slot ^ (row & 7)) << 4));
      }
    }
    #pragma unroll
    for (int n=0;n<4;n++){
      int row = wc + n*16 + (lane & 15);
      #pragma unroll
      for (int kk=0;kk<2;kk++){
        int slot = kk*4 + (lane >> 4);
        bfr[n][kk] = *(const s16x8*)(BsB + row*128 + ((slot ^ (row & 7)) << 4));
      }
    }
    #pragma unroll
    for (int kk=0;kk<2;kk++)
      #pragma unroll
      for (int m=0;m<4;m++)
        #pragma unroll
        for (int n=0;n<4;n++)
          acc[m][n] = __builtin_amdgcn_mfma_f32_16x16x32_bf16(af[m][kk], bfr[n][kk], acc[m][n], 0, 0, 0);
  }

  // C/D layout: col = lane&15, row = (lane>>4)*4 + j
  int colb = bn + wc + (lane & 15);
  int rowb = bm + wr + ((lane >> 4) << 2);
  float bb[4];
  #pragma unroll
  for (int n=0;n<4;n++) bb[n] = bias[colb + n*16];
  #pragma unroll
  for (int m=0;m<4;m++){
    #pragma unroll
    for (int n=0;n<4;n++){
      #pragma unroll
      for (int j=0;j<4;j++){
        size_t o = (size_t)(rowb + m*16 + j)*ldc + (colb + n*16);
        float val = acc[m][n][j] + bb[n];
        if (mode == 2)      ((unsigned short*)C)[o] = f2bf(val);
        else if (mode == 1) ((float*)C)[o] += val;
        else                ((float*)C)[o] = val;
      }
    }
  }
}

// ---- in-place gating: qkv[n, 1536+d] = bf16( v_v * v[n,d] ) ----
__global__ void k_vvip(unsigned short* __restrict__ qkv, const float* __restrict__ v){
  int gid = blockIdx.x*blockDim.x + threadIdx.x;   // NNODE*64
  int n = gid >> 6, d8 = (gid & 63) * 8;
  unsigned short* p = qkv + (size_t)n*2048 + 1536 + d8;
  uint4 u = *(uint4*)p;
  f4 v0 = *(const f4*)(v + (size_t)n*512 + d8);
  f4 v1 = *(const f4*)(v + (size_t)n*512 + d8 + 4);
  uint4 o;
  o.x = pack2(blo(u.x)*v0.x, bhi(u.x)*v0.y);
  o.y = pack2(blo(u.y)*v0.z, bhi(u.y)*v0.w);
  o.z = pack2(blo(u.z)*v1.x, bhi(u.z)*v1.y);
  o.w = pack2(blo(u.w)*v1.z, bhi(u.w)*v1.w);
  *(uint4*)p = o;
}

// ---- fused edge-score + aggregation: one block per destination node ----
// qkv row layout per node: [0:512) q | [512:1024) k | [1024:1536) v_s | [1536:2048) vv
__global__ __launch_bounds__(256) void k_fused(const int* __restrict__ offs,
                                               const int* __restrict__ ecol,
                                               const unsigned short* __restrict__ qkv,
                                               float* __restrict__ x,
                                               unsigned short* __restrict__ xbf,
                                               unsigned short* __restrict__ aggvbf){
  __shared__ unsigned short qs[512];
  __shared__ float ews[64];
  __shared__ int cols[64];
  int n = blockIdx.x, tid = threadIdx.x;
  int beg = offs[n], end = offs[n+1];
  if (tid < 64)
    *(uint4*)&qs[tid*8] = *(const uint4*)(qkv + (size_t)n*2048 + tid*8);
  float a0=0.f, a1=0.f, a2=0.f, a3=0.f;
  int half = tid >> 7;
  int d4 = (tid & 127) * 4;
  size_t srcoff = half ? 1536 : 1024;   // vv : v_s
  int lane = tid & 63, w = tid >> 6;

  for (int cb = beg; cb < end; cb += 64){
    int cnt = min(64, end - cb);
    __syncthreads();
    // phase 1: one wave per edge computes ew = q . k
    for (int j = w; j < cnt; j += 4){
      int c = ecol[cb + j];
      uint4 ku = *(const uint4*)(qkv + (size_t)c*2048 + 512 + lane*8);
      uint4 qu = *(const uint4*)(qs + lane*8);
      float s = blo(qu.x)*blo(ku.x) + bhi(qu.x)*bhi(ku.x)
              + blo(qu.y)*blo(ku.y) + bhi(qu.y)*bhi(ku.y)
              + blo(qu.z)*blo(ku.z) + bhi(qu.z)*bhi(ku.z)
              + blo(qu.w)*blo(ku.w) + bhi(qu.w)*bhi(ku.w);
      #pragma unroll
      for (int o=32;o;o>>=1) s += __shfl_xor(s, o, 64);
      if (lane == 0){ ews[j] = s; cols[j] = c; }
    }
    __syncthreads();
    // phase 2: all threads aggregate (half 0: v_s -> x, half 1: vv -> aggv)
    #pragma unroll 2
    for (int j = 0; j < cnt; j++){
      float wgt = ews[j];
      int c = cols[j];
      uint2 u = *(const uint2*)(qkv + (size_t)c*2048 + srcoff + d4);
      a0 += wgt*blo(u.x); a1 += wgt*bhi(u.x);
      a2 += wgt*blo(u.y); a3 += wgt*bhi(u.y);
    }
  }

  size_t base = (size_t)n*512 + d4;
  if (half == 0){
    f4 xv = *(const f4*)(x + base);
    xv.x += a0; xv.y += a1; xv.z += a2; xv.w += a3;
    *(f4*)(x + base) = xv;
    uint2 o; o.x = pack2(xv.x, xv.y); o.y = pack2(xv.z, xv.w);
    *(uint2*)(xbf + base) = o;
  } else {
    uint2 o; o.x = pack2(a0, a1); o.y = pack2(a2, a3);
    *(uint2*)(aggvbf + base) = o;
  }
}

__global__ void k_out(const int* __restrict__ tok, const float* __restrict__ x,
                      float* __restrict__ out, int out_size){
  int i = blockIdx.x*blockDim.x + threadIdx.x;
  if (i>=out_size) return;
  if (i < NNODE*DIM){
    int n = i>>9;
    out[i] = (tok[n]==PADIDX) ? 0.f : x[i];
  } else {
    int m = i - NNODE*DIM;
    out[i] = (m < NNODE && tok[m]==PADIDX) ? 1.f : 0.f;
  }
}

extern "C" void kernel_launch(void* const* d_in, const int* in_sizes, int n_in,
                              void* d_out, int out_size, void* d_ws, size_t ws_size,
                              hipStream_t stream){
  (void)in_sizes; (void)n_in; (void)ws_size;
  const int*  tok   = (const int*)d_in[0];
  const void* coord = d_in[1];
  // d_in[2] src_distance, d_in[3] src_edge_type: unused by reference
  const int*  ei    = (const int*)d_in[4];
  const void* emb   = d_in[5];
  const void* vpw   = d_in[6];
  const void* vpb   = d_in[7];
  const void* Wq    = d_in[8];
  const void* bq    = d_in[9];
  const void* Wkv   = d_in[10];
  const void* bkv   = d_in[11];
  const void* Wvm   = d_in[12];
  const void* bvm   = d_in[13];

  char* p = (char*)d_ws;
  auto alloc = [&](size_t nbytes)->char*{ char* r = p; p += (nbytes + 255) & ~(size_t)255; return r; };
  float* x      = (float*)alloc((size_t)NNODE*DIM*4);
  float* v      = (float*)alloc((size_t)NNODE*DIM*4);
  unsigned short* qkv    = (unsigned short*)alloc((size_t)NNODE*2048*2);
  unsigned short* xbf    = (unsigned short*)alloc((size_t)NNODE*DIM*2);
  unsigned short* aggvbf = (unsigned short*)alloc((size_t)NNODE*DIM*2);
  unsigned short* WqkvT  = (unsigned short*)alloc((size_t)NLAYER*2048*DIM*2);
  unsigned short* WvmT   = (unsigned short*)alloc((size_t)NLAYER*DIM*DIM*2);
  float* cEmb   = (float*)alloc((size_t)128*DIM*4);
  float* cCoord = (float*)alloc((size_t)NNODE*3*4);
  float* cVw    = (float*)alloc((size_t)3*DIM*4);
  float* cVb    = (float*)alloc((size_t)DIM*4);
  float* cbqkv  = (float*)alloc((size_t)NLAYER*2048*4);
  float* cbvm   = (float*)alloc((size_t)NLAYER*DIM*4);
  int* counts   = (int*)alloc(8192*4);
  int* offs     = (int*)alloc(8193*4);
  int* cursor   = (int*)alloc(8192*4);
  int* ecol     = (int*)alloc((size_t)NEDGE*4);
  int* flag     = (int*)alloc(4);

  k_detect<<<1,64,0,stream>>>((const unsigned short*)Wq, flag);
  auto conv = [&](const void* s, float* d, int n){
    int blocks = (n+255)/256; if (blocks>8192) blocks=8192;
    k_convert<<<blocks,256,0,stream>>>(s, d, n, flag);
  };
  conv(coord, cCoord, NNODE*3);
  conv(emb,   cEmb,   128*DIM);   // only token rows 0..127 are reachable
  conv(vpw,   cVw,    3*DIM);
  conv(vpb,   cVb,    DIM);
  conv(bvm,   cbvm,   NLAYER*DIM);
  k_bias<<<(NLAYER*2048+255)/256,256,0,stream>>>(bq, bkv, cbqkv, flag);
  // weights -> bf16 B^T: Wq rows 0..511, Wkv rows 512..2047 of combined [2048][512]
  k_convT<<<dim3((512*512+255)/256,1,NLAYER),256,0,stream>>>(Wq,  WqkvT, 512,  0,   2048*512, flag);
  k_convT<<<dim3((512*1536+255)/256,1,NLAYER),256,0,stream>>>(Wkv, WqkvT, 1536, 512, 2048*512, flag);
  k_convT<<<dim3((512*512+255)/256,1,NLAYER),256,0,stream>>>(Wvm, WvmT,  512,  0,   512*512,  flag);

  // CSR by destination, storing source col directly
  k_zero_i<<<32,256,0,stream>>>(counts, 8192);
  k_count<<<NEDGE/256,256,0,stream>>>(ei, counts);
  k_scan<<<1,1024,0,stream>>>(counts, offs, cursor);
  k_fill<<<NEDGE/256,256,0,stream>>>(ei, cursor, ecol);

  k_init<<<(NNODE*DIM)/256,256,0,stream>>>(tok, cEmb, cCoord, cVw, cVb, x, v, xbf);

  for (int l=0;l<NLAYER;l++){
    const unsigned short* WqkvT_l = WqkvT + (size_t)l*2048*DIM;
    const unsigned short* WvmT_l  = WvmT  + (size_t)l*DIM*DIM;
    const float* bqkv_l = cbqkv + (size_t)l*2048;
    const float* bvm_l  = cbvm  + (size_t)l*DIM;
    k_mgemm<<<dim3(2048/BN, NNODE/BM),256,0,stream>>>(xbf, WqkvT_l, bqkv_l, qkv, 2048, 2);
    k_vvip<<<NNODE*64/256,256,0,stream>>>(qkv, v);
    k_fused<<<NNODE,256,0,stream>>>(offs, ecol, qkv, x, xbf, aggvbf);
    k_mgemm<<<dim3(DIM/BN, NNODE/BM),256,0,stream>>>(aggvbf, WvmT_l, bvm_l, v, 512, 1);
  }

  int ob = (out_size+255)/256;
  k_out<<<ob,256,0,stream>>>(tok, x, (float*)d_out, out_size);
}